// Round 1
// 410.358 us; speedup vs baseline: 1.0336x; 1.0336x over previous
//
#include <hip/hip_runtime.h>
#include <hip/hip_bf16.h>

// Round 4: XCD-locality swizzle (T1) in gemm_k and flash_attn.
// Default round-robin block->XCD mapping puts the 8 blocks sharing an
// A-panel (gemm: grid.x==8==NXCD) / a K,V pair (flash) on 8 different
// XCDs -> dominant operand fetched ~8x from HBM (gemm A: ~268MB/dispatch,
// flash K+V: 139MB measured vs ~50 ideal). Chunked bijective remap gives
// each XCD a contiguous tile range so the shared panel is L2-resident.

using bf16 = __hip_bfloat16;
typedef __attribute__((ext_vector_type(8))) short short8;
typedef __attribute__((ext_vector_type(4))) short short4v;
typedef _Float16 half8 __attribute__((ext_vector_type(8)));
typedef __attribute__((ext_vector_type(4))) float floatx4;

#define E_DIM 1024
#define H_NUM 16
#define D_DIM 64
#define B_NUM 4
#define S_LEN 2048
#define M_TOT 8192  // B*S

__device__ __forceinline__ void async_ld16(const void* g, void* l) {
  __builtin_amdgcn_global_load_lds(
      (const __attribute__((address_space(1))) unsigned int*)g,
      (__attribute__((address_space(3))) unsigned int*)l, 16, 0, 0);
}

// fp32 -> bf16 round-to-nearest-even (ROCm cast rounding is version-dependent;
// do it explicitly). Inputs finite.
__device__ __forceinline__ short f2bf(float x) {
  unsigned u = __builtin_bit_cast(unsigned, x);
  u += 0x7FFFu + ((u >> 16) & 1u);
  return (short)(u >> 16);
}

__global__ void cvt_f32_bf16(const float* __restrict__ src,
                             short* __restrict__ dst, int n4) {
  int i = blockIdx.x * blockDim.x + threadIdx.x;
  if (i >= n4) return;
  float4 v = ((const float4*)src)[i];
  short4v o;
  o[0] = f2bf(v.x); o[1] = f2bf(v.y); o[2] = f2bf(v.z); o[3] = f2bf(v.w);
  ((short4v*)dst)[i] = o;
}

// C = A @ W^T. W is pre-rounded bf16 [N,K].
// A_F32=1: A fp32 [M,K], staged via register RNE-cvt. A_F32=0: A bf16, async.
// OUT_MODE: 0 = f16 [M,N]; 1 = bf16 [N,M] (transposed); 2 = f32 [M,N] + bias.
template <int A_F32, int OUT_MODE>
__global__ __launch_bounds__(256, 3) void gemm_k(
    const void* __restrict__ Ap, const short* __restrict__ Wb,
    const float* __restrict__ bias, void* __restrict__ Cp,
    int M, int N, int K) {
  __shared__ __align__(16) short As[128 * 32];
  __shared__ __align__(16) short Ws[128 * 32];
  const int tid = threadIdx.x;
  const int wave = tid >> 6;
  const int lane = tid & 63;
  const int quad = lane >> 4;
  const int l16 = lane & 15;
  const int wr = wave >> 1, wc = wave & 1;

  // XCD swizzle: grid is (8, 64) for every launch here (nwg=512, 512%8==0 so
  // the remap is bijective). Linear id = x + 8*y; id%8 == x, i.e. each XCD
  // would get one N-column and ALL M-tiles -> A fetched 8x. Remap so each XCD
  // owns a contiguous id range: 8 consecutive M-panels x all N-tiles; A-panel
  // read once from HBM, W (2MB bf16) stays L2-resident.
  int mBase, nBase;
  {
    const int nwg = gridDim.x * gridDim.y;        // 512
    int l = blockIdx.x + gridDim.x * blockIdx.y;
    l = (l & 7) * (nwg >> 3) + (l >> 3);
    nBase = (l & 7) * 128;                        // gridDim.x == 8
    mBase = (l >> 3) * 128;
  }

  floatx4 acc[4][4] = {};

  for (int kb = 0; kb < K; kb += 32) {
    __syncthreads();
    {
      const int sR = lane >> 2, sC = (lane & 3) * 8;
#pragma unroll
      for (int t = 0; t < 2; t++) {
        const int r0 = wave * 32 + t * 16;
        async_ld16(&Wb[(size_t)(nBase + r0 + sR) * K + kb + sC], &Ws[r0 * 32]);
      }
    }
    if (A_F32) {
      const float* A = (const float*)Ap;
      const int row = lane >> 3, colc = (lane & 7) * 4;
#pragma unroll
      for (int t = 0; t < 4; t++) {
        const int r0 = wave * 32 + t * 8 + row;
        float4 v = *(const float4*)&A[(size_t)(mBase + r0) * K + kb + colc];
        short4v o;
        o[0] = f2bf(v.x); o[1] = f2bf(v.y); o[2] = f2bf(v.z); o[3] = f2bf(v.w);
        *(short4v*)&As[r0 * 32 + colc] = o;
      }
    } else {
      const short* A = (const short*)Ap;
      const int sR = lane >> 2, sC = (lane & 3) * 8;
#pragma unroll
      for (int t = 0; t < 2; t++) {
        const int r0 = wave * 32 + t * 16;
        async_ld16(&A[(size_t)(mBase + r0 + sR) * K + kb + sC], &As[r0 * 32]);
      }
    }
    __syncthreads();

    short8 af[4], wf[4];
#pragma unroll
    for (int i = 0; i < 4; i++)
      af[i] = *(const short8*)&As[(wr * 64 + i * 16 + l16) * 32 + quad * 8];
#pragma unroll
    for (int j = 0; j < 4; j++)
      wf[j] = *(const short8*)&Ws[(wc * 64 + j * 16 + l16) * 32 + quad * 8];
#pragma unroll
    for (int i = 0; i < 4; i++)
#pragma unroll
      for (int j = 0; j < 4; j++)
        acc[i][j] = __builtin_amdgcn_mfma_f32_16x16x32_bf16(af[i], wf[j], acc[i][j], 0, 0, 0);
  }

#pragma unroll
  for (int i = 0; i < 4; i++) {
    const int row0 = mBase + wr * 64 + i * 16 + quad * 4;
#pragma unroll
    for (int j = 0; j < 4; j++) {
      const int col = nBase + wc * 64 + j * 16 + l16;
      const float bv = (OUT_MODE == 2) ? bias[col] : 0.0f;
#pragma unroll
      for (int r = 0; r < 4; r++) {
        const float val = acc[i][j][r] + bv;
        if (OUT_MODE == 0)
          ((_Float16*)Cp)[(size_t)(row0 + r) * N + col] = (_Float16)val;
        else if (OUT_MODE == 1)
          ((short*)Cp)[(size_t)col * M + (row0 + r)] = f2bf(val);
        else
          ((float*)Cp)[(size_t)(row0 + r) * N + col] = val;
      }
    }
  }
}

// Flash attention v2. q,k: f16 [M,E]; vt: bf16 [E,M]; o: bf16 [M,E].
// Softmax over UNSCALED scores (reference bug preserved), shift-by-40
// instead of running max (shift-invariant; bounds exp into fp32/bf16 range).
// Rowsum l accumulated via MFMA with a ones B-operand column.
__global__ __launch_bounds__(256, 3) void flash_attn(
    const _Float16* __restrict__ q, const _Float16* __restrict__ k,
    const short* __restrict__ vt, short* __restrict__ o) {
  __shared__ __align__(16) char smem[51200];
  short* Vts = (short*)smem;                    // bf16 [64][128] swizzled, 16KB
  _Float16* Ks = (_Float16*)(smem + 16384);     // f16 [128][64] swizzled, 16KB
  // Ps aliases Ks (Ks dead after QK): per-wave bf16 [32][136], 4x8704B
  short* PsW = (short*)(smem + 16384 + (threadIdx.x >> 6) * 8704);

  const int tid = threadIdx.x;
  const int wave = tid >> 6;
  const int lane = tid & 63;
  const int quad = lane >> 4;
  const int l16 = lane & 15;

  // XCD swizzle: grid (16,16,4) = 1024 blocks; id%8 == qtile%8, so the 16
  // q-blocks sharing one (b,h)'s K,V scatter over all XCDs -> K+V fetched 8x
  // (139MB measured vs ~50 ideal). Remap: each XCD owns 8 (b,h) pairs with
  // all their q-blocks; per-XCD K/V working set = 8 x 512KB = 4MB = L2.
  int qRow0, h, b;
  {
    int l = blockIdx.x + ((blockIdx.y + (blockIdx.z << 4)) << 4);
    l = (l & 7) * 128 + (l >> 3);               // nwg=1024, bijective
    qRow0 = (l & 15) * 128;
    h = (l >> 4) & 15;
    b = l >> 8;
  }

  const _Float16* qp = q + (size_t)(b * S_LEN + qRow0) * E_DIM + h * D_DIM;
  const _Float16* kp = k + (size_t)(b * S_LEN) * E_DIM + h * D_DIM;
  const short* vtp = vt + (size_t)(h * D_DIM) * M_TOT + b * S_LEN;
  short* op = o + (size_t)(b * S_LEN + qRow0) * E_DIM + h * D_DIM;

  half8 qf[2][2];
#pragma unroll
  for (int i = 0; i < 2; i++)
#pragma unroll
    for (int ks = 0; ks < 2; ks++)
      qf[i][ks] = *(const half8*)&qp[(size_t)(wave * 32 + i * 16 + l16) * E_DIM + ks * 32 + quad * 8];

  short8 ones;
#pragma unroll
  for (int j = 0; j < 8; j++) ones[j] = (l16 == 0) ? (short)0x3F80 : (short)0;

  floatx4 oacc[2][4] = {};
  floatx4 oaccL[2] = {};

  const int kRow = lane >> 3, kChk = lane & 7;
  const int vRow = lane >> 4, vChk = lane & 15;

  for (int kt = 0; kt < 16; kt++) {
    __syncthreads();  // (A) prior tile's Ps/Vts reads complete
#pragma unroll
    for (int t = 0; t < 4; t++) {
      const int r0 = wave * 32 + t * 8;
      const int gcol = (kChk ^ kRow) * 8;
      async_ld16(&kp[(size_t)(kt * 128 + r0 + kRow) * E_DIM + gcol], &Ks[r0 * 64]);
    }
#pragma unroll
    for (int t = 0; t < 4; t++) {
      const int r0 = wave * 16 + t * 4;
      const int row = r0 + vRow;
      const int gcol = (vChk ^ (row & 15)) * 8;
      async_ld16(&vtp[(size_t)row * M_TOT + kt * 128 + gcol], &Vts[r0 * 128]);
    }
    __syncthreads();  // (B) tiles staged

    floatx4 sc[2][8] = {};
#pragma unroll
    for (int jt = 0; jt < 8; jt++) {
#pragma unroll
      for (int ks = 0; ks < 2; ks++) {
        const int scol = ((ks * 4 + quad) ^ (l16 & 7)) * 8;
        half8 kf = *(const half8*)&Ks[(jt * 16 + l16) * 64 + scol];
        sc[0][jt] = __builtin_amdgcn_mfma_f32_16x16x32_f16(qf[0][ks], kf, sc[0][jt], 0, 0, 0);
        sc[1][jt] = __builtin_amdgcn_mfma_f32_16x16x32_f16(qf[1][ks], kf, sc[1][jt], 0, 0, 0);
      }
    }
    __syncthreads();  // (C) all Ks reads done before Ps overwrites them

    // p = exp(s - 40); softmax is shift-invariant, 40 keeps exp in range
#pragma unroll
    for (int i = 0; i < 2; i++)
#pragma unroll
      for (int r = 0; r < 4; r++) {
        const int prow = i * 16 + quad * 4 + r;
#pragma unroll
        for (int jt = 0; jt < 8; jt++) {
          const float p = __expf(sc[i][jt][r] - 40.0f);
          PsW[prow * 136 + jt * 16 + l16] = f2bf(p);
        }
      }

    // O += P @ V ; l += P @ ones (same quantized P -> consistent num/denom)
#pragma unroll
    for (int ks = 0; ks < 4; ks++) {
      short8 pf[2];
#pragma unroll
      for (int i = 0; i < 2; i++)
        pf[i] = *(const short8*)&PsW[(i * 16 + l16) * 136 + ks * 32 + quad * 8];
#pragma unroll
      for (int dt = 0; dt < 4; dt++) {
        const int scol = ((ks * 4 + quad) ^ l16) * 8;
        short8 vf = *(const short8*)&Vts[(dt * 16 + l16) * 128 + scol];
        oacc[0][dt] = __builtin_amdgcn_mfma_f32_16x16x32_bf16(pf[0], vf, oacc[0][dt], 0, 0, 0);
        oacc[1][dt] = __builtin_amdgcn_mfma_f32_16x16x32_bf16(pf[1], vf, oacc[1][dt], 0, 0, 0);
      }
      oaccL[0] = __builtin_amdgcn_mfma_f32_16x16x32_bf16(pf[0], ones, oaccL[0], 0, 0, 0);
      oaccL[1] = __builtin_amdgcn_mfma_f32_16x16x32_bf16(pf[1], ones, oaccL[1], 0, 0, 0);
    }
  }

#pragma unroll
  for (int i = 0; i < 2; i++)
#pragma unroll
    for (int r = 0; r < 4; r++) {
      // l for rows quad*4+r lives in col 0 = lane quad*16 of this quad group
      const float ls = __shfl(oaccL[i][r], lane & 48, 64);
      const float inv = 1.0f / ls;
      const int row = wave * 32 + i * 16 + quad * 4 + r;
#pragma unroll
      for (int dt = 0; dt < 4; dt++)
        op[(size_t)row * E_DIM + dt * 16 + l16] = f2bf(oacc[i][dt][r] * inv);
    }
}

extern "C" void kernel_launch(void* const* d_in, const int* in_sizes, int n_in,
                              void* d_out, int out_size, void* d_ws, size_t ws_size,
                              hipStream_t stream) {
  const float* Q  = (const float*)d_in[0];
  const float* K  = (const float*)d_in[1];
  const float* V  = (const float*)d_in[2];
  const float* Wq = (const float*)d_in[3];
  const float* Wk = (const float*)d_in[4];
  const float* Wv = (const float*)d_in[5];
  const float* Wo = (const float*)d_in[6];
  const float* bo = (const float*)d_in[7];
  float* out = (float*)d_out;

  char* ws = (char*)d_ws;
  const size_t wsz = (size_t)E_DIM * E_DIM * 2;   // 2MB per bf16 weight
  short* wqb = (short*)ws; ws += wsz;
  short* wkb = (short*)ws; ws += wsz;
  short* wvb = (short*)ws; ws += wsz;
  short* wob = (short*)ws; ws += wsz;
  const size_t asz = (size_t)M_TOT * E_DIM * 2;   // 16MB per activation
  _Float16* qw = (_Float16*)ws; ws += asz;
  _Float16* kw = (_Float16*)ws; ws += asz;
  short* vtw = (short*)ws;      ws += asz;        // bf16 [E, M]
  short* aw  = (short*)ws;      ws += asz;        // bf16 [M, E]

  dim3 blk(256);
  const int n4 = E_DIM * E_DIM / 4;
  cvt_f32_bf16<<<dim3(n4 / 256), blk, 0, stream>>>(Wq, wqb, n4);
  cvt_f32_bf16<<<dim3(n4 / 256), blk, 0, stream>>>(Wk, wkb, n4);
  cvt_f32_bf16<<<dim3(n4 / 256), blk, 0, stream>>>(Wv, wvb, n4);
  cvt_f32_bf16<<<dim3(n4 / 256), blk, 0, stream>>>(Wo, wob, n4);

  dim3 ggrid(E_DIM / 128, M_TOT / 128);
  gemm_k<1, 0><<<ggrid, blk, 0, stream>>>(Q, wqb, nullptr, qw, M_TOT, E_DIM, E_DIM);
  gemm_k<1, 0><<<ggrid, blk, 0, stream>>>(K, wkb, nullptr, kw, M_TOT, E_DIM, E_DIM);
  gemm_k<1, 1><<<ggrid, blk, 0, stream>>>(V, wvb, nullptr, vtw, M_TOT, E_DIM, E_DIM);
  flash_attn<<<dim3(S_LEN / 128, H_NUM, B_NUM), blk, 0, stream>>>(qw, kw, vtw, aw);
  gemm_k<0, 2><<<ggrid, blk, 0, stream>>>(aw, wob, bo, out, M_TOT, E_DIM, E_DIM);
}

// Round 2
// 376.349 us; speedup vs baseline: 1.1270x; 1.0904x over previous
//
#include <hip/hip_runtime.h>
#include <hip/hip_bf16.h>

// Round 5: kill the VALU-bound fp32-staging path in the proj GEMMs.
// Round-1 evidence: swizzle fixed flash FETCH (139->24.6MB) but dur ~same ->
// not memory-bound anywhere. Residual ~283us = GEMM side; the A_F32=1 path
// does 16 f2bf + 4 float4 sync loads + 4 ds_write per lane per K-iter
// (~160 VALU-cyc vs ~78 MFMA-cyc -> ~250TF -> ~70us/GEMM, matches).
// Fix: pre-convert Q/K/V to bf16 (memory-bound pass, identical RNE rounding,
// scratch = aw buffer which is dead until flash) -> all 4 GEMMs use the pure
// global_load_lds m97 path. Plus T5 setprio around flash MFMA clusters.

using bf16 = __hip_bfloat16;
typedef __attribute__((ext_vector_type(8))) short short8;
typedef __attribute__((ext_vector_type(4))) short short4v;
typedef _Float16 half8 __attribute__((ext_vector_type(8)));
typedef __attribute__((ext_vector_type(4))) float floatx4;

#define E_DIM 1024
#define H_NUM 16
#define D_DIM 64
#define B_NUM 4
#define S_LEN 2048
#define M_TOT 8192  // B*S

__device__ __forceinline__ void async_ld16(const void* g, void* l) {
  __builtin_amdgcn_global_load_lds(
      (const __attribute__((address_space(1))) unsigned int*)g,
      (__attribute__((address_space(3))) unsigned int*)l, 16, 0, 0);
}

// fp32 -> bf16 round-to-nearest-even (ROCm cast rounding is version-dependent;
// do it explicitly). Inputs finite.
__device__ __forceinline__ short f2bf(float x) {
  unsigned u = __builtin_bit_cast(unsigned, x);
  u += 0x7FFFu + ((u >> 16) & 1u);
  return (short)(u >> 16);
}

__global__ void cvt_f32_bf16(const float* __restrict__ src,
                             short* __restrict__ dst, int n4) {
  int i = blockIdx.x * blockDim.x + threadIdx.x;
  if (i >= n4) return;
  float4 v = ((const float4*)src)[i];
  short4v o;
  o[0] = f2bf(v.x); o[1] = f2bf(v.y); o[2] = f2bf(v.z); o[3] = f2bf(v.w);
  ((short4v*)dst)[i] = o;
}

// C = A @ W^T. A bf16 [M,K] (pre-rounded), W bf16 [N,K] (pre-rounded).
// Both staged via global_load_lds (m97 structure).
// OUT_MODE: 0 = f16 [M,N]; 1 = bf16 [N,M] (transposed); 2 = f32 [M,N] + bias.
template <int OUT_MODE>
__global__ __launch_bounds__(256, 3) void gemm_k(
    const short* __restrict__ A, const short* __restrict__ Wb,
    const float* __restrict__ bias, void* __restrict__ Cp,
    int M, int N, int K) {
  __shared__ __align__(16) short As[128 * 32];
  __shared__ __align__(16) short Ws[128 * 32];
  const int tid = threadIdx.x;
  const int wave = tid >> 6;
  const int lane = tid & 63;
  const int quad = lane >> 4;
  const int l16 = lane & 15;
  const int wr = wave >> 1, wc = wave & 1;

  // XCD swizzle (T1): grid (8,64), nwg=512 (bijective). Default id%8 == x
  // would give each XCD one N-column and all M-tiles -> A fetched 8x.
  // Remap so each XCD owns 8 consecutive M-panels x all N-tiles.
  int mBase, nBase;
  {
    const int nwg = gridDim.x * gridDim.y;        // 512
    int l = blockIdx.x + gridDim.x * blockIdx.y;
    l = (l & 7) * (nwg >> 3) + (l >> 3);
    nBase = (l & 7) * 128;                        // gridDim.x == 8
    mBase = (l >> 3) * 128;
  }

  floatx4 acc[4][4] = {};

  const int sR = lane >> 2, sC = (lane & 3) * 8;
  for (int kb = 0; kb < K; kb += 32) {
    __syncthreads();
#pragma unroll
    for (int t = 0; t < 2; t++) {
      const int r0 = wave * 32 + t * 16;
      async_ld16(&Wb[(size_t)(nBase + r0 + sR) * K + kb + sC], &Ws[r0 * 32]);
    }
#pragma unroll
    for (int t = 0; t < 2; t++) {
      const int r0 = wave * 32 + t * 16;
      async_ld16(&A[(size_t)(mBase + r0 + sR) * K + kb + sC], &As[r0 * 32]);
    }
    __syncthreads();

    short8 af[4], wf[4];
#pragma unroll
    for (int i = 0; i < 4; i++)
      af[i] = *(const short8*)&As[(wr * 64 + i * 16 + l16) * 32 + quad * 8];
#pragma unroll
    for (int j = 0; j < 4; j++)
      wf[j] = *(const short8*)&Ws[(wc * 64 + j * 16 + l16) * 32 + quad * 8];
#pragma unroll
    for (int i = 0; i < 4; i++)
#pragma unroll
      for (int j = 0; j < 4; j++)
        acc[i][j] = __builtin_amdgcn_mfma_f32_16x16x32_bf16(af[i], wf[j], acc[i][j], 0, 0, 0);
  }

#pragma unroll
  for (int i = 0; i < 4; i++) {
    const int row0 = mBase + wr * 64 + i * 16 + quad * 4;
#pragma unroll
    for (int j = 0; j < 4; j++) {
      const int col = nBase + wc * 64 + j * 16 + l16;
      const float bv = (OUT_MODE == 2) ? bias[col] : 0.0f;
#pragma unroll
      for (int r = 0; r < 4; r++) {
        const float val = acc[i][j][r] + bv;
        if (OUT_MODE == 0)
          ((_Float16*)Cp)[(size_t)(row0 + r) * N + col] = (_Float16)val;
        else if (OUT_MODE == 1)
          ((short*)Cp)[(size_t)col * M + (row0 + r)] = f2bf(val);
        else
          ((float*)Cp)[(size_t)(row0 + r) * N + col] = val;
      }
    }
  }
}

// Flash attention v2. q,k: f16 [M,E]; vt: bf16 [E,M]; o: bf16 [M,E].
// Softmax over UNSCALED scores (reference bug preserved), shift-by-40
// instead of running max (shift-invariant; bounds exp into fp32/bf16 range).
// Rowsum l accumulated via MFMA with a ones B-operand column.
__global__ __launch_bounds__(256, 3) void flash_attn(
    const _Float16* __restrict__ q, const _Float16* __restrict__ k,
    const short* __restrict__ vt, short* __restrict__ o) {
  __shared__ __align__(16) char smem[51200];
  short* Vts = (short*)smem;                    // bf16 [64][128] swizzled, 16KB
  _Float16* Ks = (_Float16*)(smem + 16384);     // f16 [128][64] swizzled, 16KB
  // Ps aliases Ks (Ks dead after QK): per-wave bf16 [32][136], 4x8704B
  short* PsW = (short*)(smem + 16384 + (threadIdx.x >> 6) * 8704);

  const int tid = threadIdx.x;
  const int wave = tid >> 6;
  const int lane = tid & 63;
  const int quad = lane >> 4;
  const int l16 = lane & 15;

  // XCD swizzle (T1): grid (16,16,4)=1024 blocks; remap so each XCD owns
  // 8 (b,h) pairs with all their q-blocks -> K/V working set 4MB = L2.
  int qRow0, h, b;
  {
    int l = blockIdx.x + ((blockIdx.y + (blockIdx.z << 4)) << 4);
    l = (l & 7) * 128 + (l >> 3);               // nwg=1024, bijective
    qRow0 = (l & 15) * 128;
    h = (l >> 4) & 15;
    b = l >> 8;
  }

  const _Float16* qp = q + (size_t)(b * S_LEN + qRow0) * E_DIM + h * D_DIM;
  const _Float16* kp = k + (size_t)(b * S_LEN) * E_DIM + h * D_DIM;
  const short* vtp = vt + (size_t)(h * D_DIM) * M_TOT + b * S_LEN;
  short* op = o + (size_t)(b * S_LEN + qRow0) * E_DIM + h * D_DIM;

  half8 qf[2][2];
#pragma unroll
  for (int i = 0; i < 2; i++)
#pragma unroll
    for (int ks = 0; ks < 2; ks++)
      qf[i][ks] = *(const half8*)&qp[(size_t)(wave * 32 + i * 16 + l16) * E_DIM + ks * 32 + quad * 8];

  short8 ones;
#pragma unroll
  for (int j = 0; j < 8; j++) ones[j] = (l16 == 0) ? (short)0x3F80 : (short)0;

  floatx4 oacc[2][4] = {};
  floatx4 oaccL[2] = {};

  const int kRow = lane >> 3, kChk = lane & 7;
  const int vRow = lane >> 4, vChk = lane & 15;

  for (int kt = 0; kt < 16; kt++) {
    __syncthreads();  // (A) prior tile's Ps/Vts reads complete
#pragma unroll
    for (int t = 0; t < 4; t++) {
      const int r0 = wave * 32 + t * 8;
      const int gcol = (kChk ^ kRow) * 8;
      async_ld16(&kp[(size_t)(kt * 128 + r0 + kRow) * E_DIM + gcol], &Ks[r0 * 64]);
    }
#pragma unroll
    for (int t = 0; t < 4; t++) {
      const int r0 = wave * 16 + t * 4;
      const int row = r0 + vRow;
      const int gcol = (vChk ^ (row & 15)) * 8;
      async_ld16(&vtp[(size_t)row * M_TOT + kt * 128 + gcol], &Vts[r0 * 128]);
    }
    __syncthreads();  // (B) tiles staged

    floatx4 sc[2][8] = {};
    __builtin_amdgcn_s_setprio(1);              // T5: favor MFMA-issuing wave
#pragma unroll
    for (int jt = 0; jt < 8; jt++) {
#pragma unroll
      for (int ks = 0; ks < 2; ks++) {
        const int scol = ((ks * 4 + quad) ^ (l16 & 7)) * 8;
        half8 kf = *(const half8*)&Ks[(jt * 16 + l16) * 64 + scol];
        sc[0][jt] = __builtin_amdgcn_mfma_f32_16x16x32_f16(qf[0][ks], kf, sc[0][jt], 0, 0, 0);
        sc[1][jt] = __builtin_amdgcn_mfma_f32_16x16x32_f16(qf[1][ks], kf, sc[1][jt], 0, 0, 0);
      }
    }
    __builtin_amdgcn_s_setprio(0);
    __syncthreads();  // (C) all Ks reads done before Ps overwrites them

    // p = exp(s - 40); softmax is shift-invariant, 40 keeps exp in range
#pragma unroll
    for (int i = 0; i < 2; i++)
#pragma unroll
      for (int r = 0; r < 4; r++) {
        const int prow = i * 16 + quad * 4 + r;
#pragma unroll
        for (int jt = 0; jt < 8; jt++) {
          const float p = __expf(sc[i][jt][r] - 40.0f);
          PsW[prow * 136 + jt * 16 + l16] = f2bf(p);
        }
      }

    // O += P @ V ; l += P @ ones (same quantized P -> consistent num/denom)
    __builtin_amdgcn_s_setprio(1);
#pragma unroll
    for (int ks = 0; ks < 4; ks++) {
      short8 pf[2];
#pragma unroll
      for (int i = 0; i < 2; i++)
        pf[i] = *(const short8*)&PsW[(i * 16 + l16) * 136 + ks * 32 + quad * 8];
#pragma unroll
      for (int dt = 0; dt < 4; dt++) {
        const int scol = ((ks * 4 + quad) ^ l16) * 8;
        short8 vf = *(const short8*)&Vts[(dt * 16 + l16) * 128 + scol];
        oacc[0][dt] = __builtin_amdgcn_mfma_f32_16x16x32_bf16(pf[0], vf, oacc[0][dt], 0, 0, 0);
        oacc[1][dt] = __builtin_amdgcn_mfma_f32_16x16x32_bf16(pf[1], vf, oacc[1][dt], 0, 0, 0);
      }
      oaccL[0] = __builtin_amdgcn_mfma_f32_16x16x32_bf16(pf[0], ones, oaccL[0], 0, 0, 0);
      oaccL[1] = __builtin_amdgcn_mfma_f32_16x16x32_bf16(pf[1], ones, oaccL[1], 0, 0, 0);
    }
    __builtin_amdgcn_s_setprio(0);
  }

#pragma unroll
  for (int i = 0; i < 2; i++)
#pragma unroll
    for (int r = 0; r < 4; r++) {
      // l for rows quad*4+r lives in col 0 = lane quad*16 of this quad group
      const float ls = __shfl(oaccL[i][r], lane & 48, 64);
      const float inv = 1.0f / ls;
      const int row = wave * 32 + i * 16 + quad * 4 + r;
#pragma unroll
      for (int dt = 0; dt < 4; dt++)
        op[(size_t)row * E_DIM + dt * 16 + l16] = f2bf(oacc[i][dt][r] * inv);
    }
}

extern "C" void kernel_launch(void* const* d_in, const int* in_sizes, int n_in,
                              void* d_out, int out_size, void* d_ws, size_t ws_size,
                              hipStream_t stream) {
  const float* Q  = (const float*)d_in[0];
  const float* K  = (const float*)d_in[1];
  const float* V  = (const float*)d_in[2];
  const float* Wq = (const float*)d_in[3];
  const float* Wk = (const float*)d_in[4];
  const float* Wv = (const float*)d_in[5];
  const float* Wo = (const float*)d_in[6];
  const float* bo = (const float*)d_in[7];
  float* out = (float*)d_out;

  char* ws = (char*)d_ws;
  const size_t wsz = (size_t)E_DIM * E_DIM * 2;   // 2MB per bf16 weight
  short* wqb = (short*)ws; ws += wsz;
  short* wkb = (short*)ws; ws += wsz;
  short* wvb = (short*)ws; ws += wsz;
  short* wob = (short*)ws; ws += wsz;
  const size_t asz = (size_t)M_TOT * E_DIM * 2;   // 16MB per activation
  _Float16* qw = (_Float16*)ws; ws += asz;
  _Float16* kw = (_Float16*)ws; ws += asz;
  short* vtw = (short*)ws;      ws += asz;        // bf16 [E, M]
  short* aw  = (short*)ws;      ws += asz;        // bf16 [M, E]
  // aw doubles as bf16 scratch for the pre-converted activations: it is dead
  // until flash writes it, and each proj GEMM consumes the scratch before the
  // next cvt overwrites it (stream-serialized).
  short* abf = aw;

  dim3 blk(256);
  const int n4w = E_DIM * E_DIM / 4;
  cvt_f32_bf16<<<dim3(n4w / 256), blk, 0, stream>>>(Wq, wqb, n4w);
  cvt_f32_bf16<<<dim3(n4w / 256), blk, 0, stream>>>(Wk, wkb, n4w);
  cvt_f32_bf16<<<dim3(n4w / 256), blk, 0, stream>>>(Wv, wvb, n4w);
  cvt_f32_bf16<<<dim3(n4w / 256), blk, 0, stream>>>(Wo, wob, n4w);

  const int n4a = M_TOT * E_DIM / 4;
  dim3 ggrid(E_DIM / 128, M_TOT / 128);
  cvt_f32_bf16<<<dim3(n4a / 256), blk, 0, stream>>>(Q, abf, n4a);
  gemm_k<0><<<ggrid, blk, 0, stream>>>(abf, wqb, nullptr, qw, M_TOT, E_DIM, E_DIM);
  cvt_f32_bf16<<<dim3(n4a / 256), blk, 0, stream>>>(K, abf, n4a);
  gemm_k<0><<<ggrid, blk, 0, stream>>>(abf, wkb, nullptr, kw, M_TOT, E_DIM, E_DIM);
  cvt_f32_bf16<<<dim3(n4a / 256), blk, 0, stream>>>(V, abf, n4a);
  gemm_k<1><<<ggrid, blk, 0, stream>>>(abf, wvb, nullptr, vtw, M_TOT, E_DIM, E_DIM);
  flash_attn<<<dim3(S_LEN / 128, H_NUM, B_NUM), blk, 0, stream>>>(qw, kw, vtw, aw);
  gemm_k<2><<<ggrid, blk, 0, stream>>>(aw, wob, bo, out, M_TOT, E_DIM, E_DIM);
}

// Round 3
// 331.676 us; speedup vs baseline: 1.2788x; 1.1347x over previous
//
#include <hip/hip_runtime.h>
#include <hip/hip_bf16.h>

// Round 6: GEMM-side restructure. Round-2 evidence: proj GEMMs ~55us each
// (~310TF) despite pure gload_lds path. Causes: (1) 512-block grid = 2
// blocks/CU, no refill; (2) BK=32 -> 32 vmcnt(0) barrier drains per block;
// (3) V^T GEMM scalar 2B stores at stride 16KB (~8x write amp).
// Fixes: batch QKV proj into one 1536-block dispatch (3/CU + refill,
// XCD-chunked decode); BK=64 with XOR-swizzled LDS (both-sides pattern);
// V^T store restaged through LDS for short8-coalesced writes; cvts fused
// 7->2 launches, scratch in d_out (dead until final GEMM). Flash unchanged.

using bf16 = __hip_bfloat16;
typedef __attribute__((ext_vector_type(8))) short short8;
typedef __attribute__((ext_vector_type(4))) short short4v;
typedef _Float16 half8 __attribute__((ext_vector_type(8)));
typedef __attribute__((ext_vector_type(4))) float floatx4;

#define E_DIM 1024
#define H_NUM 16
#define D_DIM 64
#define B_NUM 4
#define S_LEN 2048
#define M_TOT 8192  // B*S

__device__ __forceinline__ void async_ld16(const void* g, void* l) {
  __builtin_amdgcn_global_load_lds(
      (const __attribute__((address_space(1))) unsigned int*)g,
      (__attribute__((address_space(3))) unsigned int*)l, 16, 0, 0);
}

// fp32 -> bf16 round-to-nearest-even (explicit; ROCm cast rounding is
// version-dependent). Inputs finite.
__device__ __forceinline__ short f2bf(float x) {
  unsigned u = __builtin_bit_cast(unsigned, x);
  u += 0x7FFFu + ((u >> 16) & 1u);
  return (short)(u >> 16);
}

// 4 weight matrices in one dispatch. grid (E*E/4/256, 4).
__global__ void cvt_w4(const float* __restrict__ a, const float* __restrict__ b,
                       const float* __restrict__ c, const float* __restrict__ d,
                       short* __restrict__ oa, short* __restrict__ ob,
                       short* __restrict__ oc, short* __restrict__ od) {
  const int z = blockIdx.y;
  const float* src = z == 0 ? a : z == 1 ? b : z == 2 ? c : d;
  short* dst = z == 0 ? oa : z == 1 ? ob : z == 2 ? oc : od;
  const int i = blockIdx.x * blockDim.x + threadIdx.x;
  float4 v = ((const float4*)src)[i];
  short4v o;
  o[0] = f2bf(v.x); o[1] = f2bf(v.y); o[2] = f2bf(v.z); o[3] = f2bf(v.w);
  ((short4v*)dst)[i] = o;
}

// Q,K,V activations in one dispatch. grid (M*E/4/256, 3).
__global__ void cvt_a3(const float* __restrict__ a, const float* __restrict__ b,
                       const float* __restrict__ c, short* __restrict__ oa,
                       short* __restrict__ ob, short* __restrict__ oc) {
  const int z = blockIdx.y;
  const float* src = z == 0 ? a : z == 1 ? b : c;
  short* dst = z == 0 ? oa : z == 1 ? ob : oc;
  const int i = blockIdx.x * blockDim.x + threadIdx.x;
  float4 v = ((const float4*)src)[i];
  short4v o;
  o[0] = f2bf(v.x); o[1] = f2bf(v.y); o[2] = f2bf(v.z); o[3] = f2bf(v.w);
  ((short4v*)dst)[i] = o;
}

// C = A @ W^T, A bf16 [M,K], W bf16 [N,K], both via global_load_lds with
// XOR-swizzled LDS (BK=64: linear layout would be 16-way bank conflict).
// MODE 0: QKV batch, grid (8,64,3). z=0/1 -> f16 [M,N]; z=2 -> bf16 [N,M]
//         via LDS-restaged coalesced short8 stores.
// MODE 2: single, grid (8,64,1), f32 [M,N] + bias.
// Decode: xcd = blockIdx.x owns M-panels [x*8, x*8+8) x all N x all z ->
// per-phase L2 working set ~4MB (A-panel 2MB + W 2MB).
template <int MODE>
__global__ __launch_bounds__(256, 3) void gemm_k(
    const short* __restrict__ A0, const short* __restrict__ A1,
    const short* __restrict__ A2, const short* __restrict__ W0,
    const short* __restrict__ W1, const short* __restrict__ W2,
    void* __restrict__ C0, void* __restrict__ C1p, void* __restrict__ C2p,
    const float* __restrict__ bias) {
  __shared__ __align__(16) char smem[MODE == 0 ? 34816 : 32768];
  short* As = (short*)smem;            // bf16 [128][64] swizzled
  short* Ws = (short*)(smem + 16384);  // bf16 [128][64] swizzled
  short* Cs = (short*)smem;            // bf16 [128][136] (z==2 epilogue only)

  const int M = M_TOT, N = E_DIM, K = E_DIM;
  const int tid = threadIdx.x;
  const int wave = tid >> 6;
  const int lane = tid & 63;
  const int quad = lane >> 4;
  const int l16 = lane & 15;
  const int wr = wave >> 1, wc = wave & 1;

  const int z = (MODE == 0) ? blockIdx.z : 0;
  const short* A = (MODE == 0) ? (z == 0 ? A0 : z == 1 ? A1 : A2) : A0;
  const short* W = (MODE == 0) ? (z == 0 ? W0 : z == 1 ? W1 : W2) : W0;

  const int nBase = (blockIdx.y & 7) * 128;
  const int mBase = (blockIdx.x * 8 + (blockIdx.y >> 3)) * 128;

  // Staging source swizzle: dest row r (r%8 pattern = lane>>3), position
  // s = lane&7 holds global col-group s ^ (r&7). Read side applies same XOR.
  const int sRow = lane >> 3;
  const int sSwz = ((lane & 7) ^ sRow) * 8;
  const int rdSwz0 = ((0 * 4 + quad) ^ (l16 & 7)) * 8;
  const int rdSwz1 = ((1 * 4 + quad) ^ (l16 & 7)) * 8;

  floatx4 acc[4][4] = {};

  for (int kb = 0; kb < K; kb += 64) {
    __syncthreads();
#pragma unroll
    for (int t = 0; t < 4; t++) {
      const int r0 = wave * 32 + t * 8;
      async_ld16(&W[(size_t)(nBase + r0 + sRow) * K + kb + sSwz], &Ws[r0 * 64]);
      async_ld16(&A[(size_t)(mBase + r0 + sRow) * K + kb + sSwz], &As[r0 * 64]);
    }
    __syncthreads();
#pragma unroll
    for (int ks = 0; ks < 2; ks++) {
      const int rs = ks ? rdSwz1 : rdSwz0;
      short8 af[4], wf[4];
#pragma unroll
      for (int i = 0; i < 4; i++)
        af[i] = *(const short8*)&As[(wr * 64 + i * 16 + l16) * 64 + rs];
#pragma unroll
      for (int j = 0; j < 4; j++)
        wf[j] = *(const short8*)&Ws[(wc * 64 + j * 16 + l16) * 64 + rs];
#pragma unroll
      for (int i = 0; i < 4; i++)
#pragma unroll
        for (int j = 0; j < 4; j++)
          acc[i][j] = __builtin_amdgcn_mfma_f32_16x16x32_bf16(af[i], wf[j], acc[i][j], 0, 0, 0);
    }
  }

  if (MODE == 2) {
#pragma unroll
    for (int i = 0; i < 4; i++) {
      const int row0 = mBase + wr * 64 + i * 16 + quad * 4;
#pragma unroll
      for (int j = 0; j < 4; j++) {
        const int col = nBase + wc * 64 + j * 16 + l16;
        const float bv = bias[col];
#pragma unroll
        for (int r = 0; r < 4; r++)
          ((float*)C0)[(size_t)(row0 + r) * N + col] = acc[i][j][r] + bv;
      }
    }
  } else if (z != 2) {
    _Float16* C = (_Float16*)(z == 0 ? C0 : C1p);
#pragma unroll
    for (int i = 0; i < 4; i++) {
      const int row0 = mBase + wr * 64 + i * 16 + quad * 4;
#pragma unroll
      for (int j = 0; j < 4; j++) {
        const int col = nBase + wc * 64 + j * 16 + l16;
#pragma unroll
        for (int r = 0; r < 4; r++)
          C[(size_t)(row0 + r) * N + col] = (_Float16)acc[i][j][r];
      }
    }
  } else {
    // bf16 [N,M]: restage through LDS, store coalesced short8 rows of C^T.
    __syncthreads();  // all LDS fragment reads done before Cs overwrites
#pragma unroll
    for (int i = 0; i < 4; i++) {
      const int rl = wr * 64 + i * 16 + quad * 4;
#pragma unroll
      for (int j = 0; j < 4; j++) {
        const int cl = wc * 64 + j * 16 + l16;
#pragma unroll
        for (int r = 0; r < 4; r++)
          Cs[cl * 136 + rl + r] = f2bf(acc[i][j][r]);
      }
    }
    __syncthreads();
    short* C = (short*)C2p;
#pragma unroll
    for (int p = 0; p < 8; p++) {
      const int id = p * 256 + tid;
      const int nl = id >> 4, mc = (id & 15) * 8;
      *(short8*)&C[(size_t)(nBase + nl) * M + mBase + mc] =
          *(const short8*)&Cs[nl * 136 + mc];
    }
  }
}

// Flash attention v2 (unchanged from round 5). q,k: f16 [M,E]; vt: bf16
// [E,M]; o: bf16 [M,E]. Softmax over UNSCALED scores (reference bug
// preserved), shift-by-40; rowsum via ones-MFMA; T1 swizzle + T5 setprio.
__global__ __launch_bounds__(256, 3) void flash_attn(
    const _Float16* __restrict__ q, const _Float16* __restrict__ k,
    const short* __restrict__ vt, short* __restrict__ o) {
  __shared__ __align__(16) char smem[51200];
  short* Vts = (short*)smem;                    // bf16 [64][128] swizzled, 16KB
  _Float16* Ks = (_Float16*)(smem + 16384);     // f16 [128][64] swizzled, 16KB
  short* PsW = (short*)(smem + 16384 + (threadIdx.x >> 6) * 8704);

  const int tid = threadIdx.x;
  const int wave = tid >> 6;
  const int lane = tid & 63;
  const int quad = lane >> 4;
  const int l16 = lane & 15;

  int qRow0, h, b;
  {
    int l = blockIdx.x + ((blockIdx.y + (blockIdx.z << 4)) << 4);
    l = (l & 7) * 128 + (l >> 3);               // nwg=1024, bijective
    qRow0 = (l & 15) * 128;
    h = (l >> 4) & 15;
    b = l >> 8;
  }

  const _Float16* qp = q + (size_t)(b * S_LEN + qRow0) * E_DIM + h * D_DIM;
  const _Float16* kp = k + (size_t)(b * S_LEN) * E_DIM + h * D_DIM;
  const short* vtp = vt + (size_t)(h * D_DIM) * M_TOT + b * S_LEN;
  short* op = o + (size_t)(b * S_LEN + qRow0) * E_DIM + h * D_DIM;

  half8 qf[2][2];
#pragma unroll
  for (int i = 0; i < 2; i++)
#pragma unroll
    for (int ks = 0; ks < 2; ks++)
      qf[i][ks] = *(const half8*)&qp[(size_t)(wave * 32 + i * 16 + l16) * E_DIM + ks * 32 + quad * 8];

  short8 ones;
#pragma unroll
  for (int j = 0; j < 8; j++) ones[j] = (l16 == 0) ? (short)0x3F80 : (short)0;

  floatx4 oacc[2][4] = {};
  floatx4 oaccL[2] = {};

  const int kRow = lane >> 3, kChk = lane & 7;
  const int vRow = lane >> 4, vChk = lane & 15;

  for (int kt = 0; kt < 16; kt++) {
    __syncthreads();  // (A) prior tile's Ps/Vts reads complete
#pragma unroll
    for (int t = 0; t < 4; t++) {
      const int r0 = wave * 32 + t * 8;
      const int gcol = (kChk ^ kRow) * 8;
      async_ld16(&kp[(size_t)(kt * 128 + r0 + kRow) * E_DIM + gcol], &Ks[r0 * 64]);
    }
#pragma unroll
    for (int t = 0; t < 4; t++) {
      const int r0 = wave * 16 + t * 4;
      const int row = r0 + vRow;
      const int gcol = (vChk ^ (row & 15)) * 8;
      async_ld16(&vtp[(size_t)row * M_TOT + kt * 128 + gcol], &Vts[r0 * 128]);
    }
    __syncthreads();  // (B) tiles staged

    floatx4 sc[2][8] = {};
    __builtin_amdgcn_s_setprio(1);
#pragma unroll
    for (int jt = 0; jt < 8; jt++) {
#pragma unroll
      for (int ks = 0; ks < 2; ks++) {
        const int scol = ((ks * 4 + quad) ^ (l16 & 7)) * 8;
        half8 kf = *(const half8*)&Ks[(jt * 16 + l16) * 64 + scol];
        sc[0][jt] = __builtin_amdgcn_mfma_f32_16x16x32_f16(qf[0][ks], kf, sc[0][jt], 0, 0, 0);
        sc[1][jt] = __builtin_amdgcn_mfma_f32_16x16x32_f16(qf[1][ks], kf, sc[1][jt], 0, 0, 0);
      }
    }
    __builtin_amdgcn_s_setprio(0);
    __syncthreads();  // (C) all Ks reads done before Ps overwrites them

    // p = exp(s - 40); softmax is shift-invariant, 40 keeps exp in range
#pragma unroll
    for (int i = 0; i < 2; i++)
#pragma unroll
      for (int r = 0; r < 4; r++) {
        const int prow = i * 16 + quad * 4 + r;
#pragma unroll
        for (int jt = 0; jt < 8; jt++) {
          const float p = __expf(sc[i][jt][r] - 40.0f);
          PsW[prow * 136 + jt * 16 + l16] = f2bf(p);
        }
      }

    __builtin_amdgcn_s_setprio(1);
#pragma unroll
    for (int ks = 0; ks < 4; ks++) {
      short8 pf[2];
#pragma unroll
      for (int i = 0; i < 2; i++)
        pf[i] = *(const short8*)&PsW[(i * 16 + l16) * 136 + ks * 32 + quad * 8];
#pragma unroll
      for (int dt = 0; dt < 4; dt++) {
        const int scol = ((ks * 4 + quad) ^ l16) * 8;
        short8 vf = *(const short8*)&Vts[(dt * 16 + l16) * 128 + scol];
        oacc[0][dt] = __builtin_amdgcn_mfma_f32_16x16x32_bf16(pf[0], vf, oacc[0][dt], 0, 0, 0);
        oacc[1][dt] = __builtin_amdgcn_mfma_f32_16x16x32_bf16(pf[1], vf, oacc[1][dt], 0, 0, 0);
      }
      oaccL[0] = __builtin_amdgcn_mfma_f32_16x16x32_bf16(pf[0], ones, oaccL[0], 0, 0, 0);
      oaccL[1] = __builtin_amdgcn_mfma_f32_16x16x32_bf16(pf[1], ones, oaccL[1], 0, 0, 0);
    }
    __builtin_amdgcn_s_setprio(0);
  }

#pragma unroll
  for (int i = 0; i < 2; i++)
#pragma unroll
    for (int r = 0; r < 4; r++) {
      const float ls = __shfl(oaccL[i][r], lane & 48, 64);
      const float inv = 1.0f / ls;
      const int row = wave * 32 + i * 16 + quad * 4 + r;
#pragma unroll
      for (int dt = 0; dt < 4; dt++)
        op[(size_t)row * E_DIM + dt * 16 + l16] = f2bf(oacc[i][dt][r] * inv);
    }
}

extern "C" void kernel_launch(void* const* d_in, const int* in_sizes, int n_in,
                              void* d_out, int out_size, void* d_ws, size_t ws_size,
                              hipStream_t stream) {
  const float* Q  = (const float*)d_in[0];
  const float* K  = (const float*)d_in[1];
  const float* V  = (const float*)d_in[2];
  const float* Wq = (const float*)d_in[3];
  const float* Wk = (const float*)d_in[4];
  const float* Wv = (const float*)d_in[5];
  const float* Wo = (const float*)d_in[6];
  const float* bo = (const float*)d_in[7];
  float* out = (float*)d_out;

  char* ws = (char*)d_ws;
  const size_t wsz = (size_t)E_DIM * E_DIM * 2;   // 2MB per bf16 weight
  short* wqb = (short*)ws; ws += wsz;
  short* wkb = (short*)ws; ws += wsz;
  short* wvb = (short*)ws; ws += wsz;
  short* wob = (short*)ws; ws += wsz;
  const size_t asz = (size_t)M_TOT * E_DIM * 2;   // 16MB per activation
  _Float16* qw = (_Float16*)ws; ws += asz;
  _Float16* kw = (_Float16*)ws; ws += asz;
  short* vtw = (short*)ws;      ws += asz;        // bf16 [E, M]
  short* aw  = (short*)ws;      ws += asz;        // bf16 [M, E]
  // bf16 activation scratch, all dead before their final consumers:
  // qbf -> aw (flash writes aw later); kbf, vbf -> d_out (final GEMM writes
  // out last). Zero extra workspace.
  short* qbf = aw;
  short* kbf = (short*)d_out;
  short* vbf = (short*)d_out + (size_t)M_TOT * E_DIM;

  dim3 blk(256);
  cvt_w4<<<dim3(E_DIM * E_DIM / 4 / 256, 4), blk, 0, stream>>>(
      Wq, Wk, Wv, Wo, wqb, wkb, wvb, wob);
  cvt_a3<<<dim3(M_TOT * E_DIM / 4 / 256, 3), blk, 0, stream>>>(
      Q, K, V, qbf, kbf, vbf);

  gemm_k<0><<<dim3(8, 64, 3), blk, 0, stream>>>(
      qbf, kbf, vbf, wqb, wkb, wvb, qw, kw, vtw, nullptr);
  flash_attn<<<dim3(S_LEN / 128, H_NUM, B_NUM), blk, 0, stream>>>(qw, kw, vtw, aw);
  gemm_k<2><<<dim3(8, 64, 1), blk, 0, stream>>>(
      aw, nullptr, nullptr, wob, nullptr, nullptr, out, nullptr, nullptr, bo);
}